// Round 5
// baseline (43.849 us; speedup 1.0000x reference)
//
#include <hip/hip_runtime.h>
#include <math.h>

#define NB   64
#define H_   384
#define W_   384
#define NR   12
#define NC   12
#define NSEL 36
#define NPART 8

// ws layout: [0,2048): float pmin[64][8]; [2048,4096): float pmax[64][8]

__global__ __launch_bounds__(256) void k_minmax(const float* __restrict__ sino,
                                                float* __restrict__ pmin,
                                                float* __restrict__ pmax){
    int b = blockIdx.x >> 3;
    int part = blockIdx.x & 7;
    const float4* src = (const float4*)(sino + (size_t)b * (H_ * W_));
    int base = part * 4608 + threadIdx.x;   // 36864 float4 / batch, 4608 / part
    float mn = 1e30f, mx = -1e30f;
    #pragma unroll
    for (int k = 0; k < 18; k++){
        float4 v = src[base + k * 256];
        mn = fminf(mn, fminf(fminf(v.x, v.y), fminf(v.z, v.w)));
        mx = fmaxf(mx, fmaxf(fmaxf(v.x, v.y), fmaxf(v.z, v.w)));
    }
    #pragma unroll
    for (int off = 32; off > 0; off >>= 1){
        mn = fminf(mn, __shfl_down(mn, off));
        mx = fmaxf(mx, __shfl_down(mx, off));
    }
    __shared__ float smn[4], smx[4];
    int lane = threadIdx.x & 63, wv = threadIdx.x >> 6;
    if (lane == 0){ smn[wv] = mn; smx[wv] = mx; }
    __syncthreads();
    if (threadIdx.x == 0){
        mn = fminf(fminf(smn[0], smn[1]), fminf(smn[2], smn[3]));
        mx = fmaxf(fmaxf(smx[0], smx[1]), fmaxf(smx[2], smx[3]));
        pmin[b * NPART + part] = mn;   // race-free overwrite: no init needed
        pmax[b * NPART + part] = mx;
    }
}

__device__ inline int binval(float x, float mn, float denom){
    float nrm = (x - mn) / denom;                 // mirror reference op order exactly
    nrm = fminf(fmaxf(nrm, 0.0f), 1.0f);
    int bn = (int)(nrm * 63.0f);                  // truncation, like astype(int32)
    bn = bn < 0 ? 0 : (bn > 63 ? 63 : bn);
    return bn;
}

__device__ inline unsigned int bytesad(unsigned int a, unsigned int b, unsigned int acc){
#if __has_builtin(__builtin_amdgcn_sad_u8)
    return __builtin_amdgcn_sad_u8(a, b, acc);
#else
    unsigned int s = acc;
    #pragma unroll
    for (int k = 0; k < 4; k++){
        int av = (a >> (8 * k)) & 255;
        int bv = (b >> (8 * k)) & 255;
        int d = av - bv;
        s += (unsigned int)(d < 0 ? -d : d);
    }
    return s;
#endif
}

// Fused bin+MI. Block = (batch, sel-row sr6, col-half). Stages a 5x8-patch
// binned region in LDS, then computes 3 selected patches' MI from LDS only.
// hist: 64 rows x 33 words (padded; 2 u16 counters per word, bv pairs).
__global__ __launch_bounds__(512, 6) void k_binmi(const float* __restrict__ sino,
                                                  const float* __restrict__ pmin,
                                                  const float* __restrict__ pmax,
                                                  float* __restrict__ out){
    int bid = blockIdx.x;
    int b = bid / 12;
    int rem = bid - b * 12;
    int sr6 = rem >> 1, chalf = rem & 1;
    int sr = sr6 << 1;
    int r0 = sr - 2; if (r0 < 0) r0 = 0;
    int r1 = sr + 2; if (r1 > NR - 1) r1 = NR - 1;
    int nrp = r1 - r0 + 1;                 // 3..5 staged patch rows
    int c0 = chalf << 2;                   // staged patch cols c0..c0+7

    __shared__ unsigned char patl[5 * 8 * 1024];   // 40 KB binned region
    __shared__ unsigned int hist[2112];            // 64*33 padded joint hist
    __shared__ unsigned int distArr[25];
    __shared__ int bestOffSh;
    __shared__ float rterm[64], cterm[64], wred[8];

    int tid = threadIdx.x;
    int lane = tid & 63, wv = tid >> 6;

    float mn = 1e30f, mx = -1e30f;
    #pragma unroll
    for (int k = 0; k < NPART; k++){       // uniform addresses -> scalar loads
        mn = fminf(mn, pmin[b * NPART + k]);
        mx = fmaxf(mx, pmax[b * NPART + k]);
    }
    float denom = mx - mn + 1e-6f;

    // ---- phase A: bin region into LDS (rows r0..r1, cols c0..c0+7) ----
    {
        const float* sbase = sino + ((size_t)b * H_ + (size_t)r0 * 32) * W_ + c0 * 32;
        int total4 = nrp << 11;            // nrp*32 rows x 64 float4/row
        for (int idx4 = tid; idx4 < total4; idx4 += 512){
            int r  = idx4 >> 6;            // region image-row
            int cc = (idx4 & 63) << 2;     // region col (floats)
            float4 v = *(const float4*)(sbase + (size_t)r * W_ + cc);
            uchar4 o;
            o.x = (unsigned char)binval(v.x, mn, denom);
            o.y = (unsigned char)binval(v.y, mn, denom);
            o.z = (unsigned char)binval(v.z, mn, denom);
            o.w = (unsigned char)binval(v.w, mn, denom);
            int pr = r >> 5, i = r & 31;
            int pc = cc >> 5, j = cc & 31;
            *(uchar4*)(patl + (((pr << 3) + pc) << 10) + i * 32 + j) = o;
        }
    }
    __syncthreads();

    const float invP = 1.0f / 1024.0f;
    for (int si = 0; si < 3; si++){
        int scS = chalf * 6 + si * 2;
        int pself = sr * NC + scS;
        int selOff = (((sr - r0) << 3) + (scS - c0)) << 10;

        // (a) zero hist  +  (b) distances (independent, share one barrier)
        for (int k = tid; k < 2112; k += 512) hist[k] = 0;

        int grp = tid >> 4, sl = tid & 15;   // 32 groups of 16 lanes; 25 active
        if (grp < 25){
            int dr = grp / 5 - 2, dc = grp % 5 - 2;
            int rr = sr + dr;  rr = rr < 0 ? 0 : (rr > NR - 1 ? NR - 1 : rr);
            int cc2 = scS + dc; cc2 = cc2 < 0 ? 0 : (cc2 > NC - 1 ? NC - 1 : cc2);
            int cid = rr * NC + cc2;
            const uint4* cp = (const uint4*)(patl + ((((rr - r0) << 3) + (cc2 - c0)) << 10));
            const uint4* sp = (const uint4*)(patl + selOff);
            unsigned int dist = 0;
            #pragma unroll
            for (int k = 0; k < 4; k++){
                uint4 cv = cp[sl + (k << 4)];
                uint4 sv = sp[sl + (k << 4)];
                dist = bytesad(cv.x, sv.x, dist);
                dist = bytesad(cv.y, sv.y, dist);
                dist = bytesad(cv.z, sv.z, dist);
                dist = bytesad(cv.w, sv.w, dist);
            }
            #pragma unroll
            for (int off = 8; off > 0; off >>= 1) dist += __shfl_xor(dist, off);
            // sentinel 0x00FFFFFF: > any real dist (<=64512), keeps key in 32 bits
            if (sl == 0) distArr[grp] = (cid == pself) ? 0x00FFFFFFu : dist;
        }
        __syncthreads();                       // S1

        // (c) wave-parallel first-min argmin: key = dist*32 + c
        if (tid < 64){
            unsigned int key = (tid < 25) ? (distArr[tid] * 32u + (unsigned int)tid)
                                          : 0xFFFFFFFFu;
            #pragma unroll
            for (int off = 32; off > 0; off >>= 1){
                unsigned int o = __shfl_xor(key, off);
                if (o < key) key = o;
            }
            if (tid == 0){
                int bc = (int)(key & 31u);
                int dr = bc / 5 - 2, dc = bc % 5 - 2;
                int rr = sr + dr;  rr = rr < 0 ? 0 : (rr > NR - 1 ? NR - 1 : rr);
                int cc2 = scS + dc; cc2 = cc2 < 0 ? 0 : (cc2 > NC - 1 ? NC - 1 : cc2);
                bestOffSh = (((rr - r0) << 3) + (cc2 - c0)) << 10;
            }
        }
        __syncthreads();                       // S2

        // (d) joint histogram: 2 elements/thread, packed u16 atomics
        {
            int boff = bestOffSh;
            unsigned int sw = *(const unsigned short*)(patl + selOff + tid * 2);
            unsigned int bw = *(const unsigned short*)(patl + boff  + tid * 2);
            unsigned int sv0 = sw & 255u, sv1 = (sw >> 8) & 255u;
            unsigned int bv0 = bw & 255u, bv1 = (bw >> 8) & 255u;
            atomicAdd(&hist[sv0 * 33 + (bv0 >> 1)], 1u << ((bv0 & 1) << 4));
            atomicAdd(&hist[sv1 * 33 + (bv1 >> 1)], 1u << ((bv1 & 1) << 4));
        }
        __syncthreads();                       // S3

        // (e) entropy partials
        {   // h_xy: ~4.125 words/thread (padding words are zero -> skipped)
            float part = 0.0f;
            #pragma unroll
            for (int k = 0; k < 5; k++){
                int w = tid + (k << 9);
                if (w < 2112){
                    unsigned int hv = hist[w];
                    unsigned int clo = hv & 0xFFFFu, chi = hv >> 16;
                    if (clo){ float p = (float)clo * invP; part -= p * __logf(p + 1e-8f); }
                    if (chi){ float p = (float)chi * invP; part -= p * __logf(p + 1e-8f); }
                }
            }
            #pragma unroll
            for (int off = 32; off > 0; off >>= 1) part += __shfl_down(part, off);
            if (lane == 0) wred[wv] = part;
        }
        {   // p_x: 8 threads per row (padded layout spreads banks)
            int sv = tid >> 3, q = tid & 7;
            unsigned int cnt = 0;
            #pragma unroll
            for (int i2 = 0; i2 < 4; i2++){
                unsigned int hv = hist[sv * 33 + q * 4 + i2];
                cnt += (hv & 0xFFFFu) + (hv >> 16);
            }
            cnt += __shfl_xor(cnt, 1); cnt += __shfl_xor(cnt, 2); cnt += __shfl_xor(cnt, 4);
            if (q == 0){
                float pm = (float)cnt * invP;
                rterm[sv] = cnt ? -pm * __logf(pm + 1e-8f) : 0.0f;
            }
        }
        {   // p_y: 8 threads per column; stride-33 words -> banks rotate per sv
            int bv = tid >> 3, q = tid & 7;
            int w0 = bv >> 1, sh = (bv & 1) << 4;
            unsigned int cnt = 0;
            #pragma unroll
            for (int m = 0; m < 8; m++){
                cnt += (hist[(q * 8 + m) * 33 + w0] >> sh) & 0xFFFFu;
            }
            cnt += __shfl_xor(cnt, 1); cnt += __shfl_xor(cnt, 2); cnt += __shfl_xor(cnt, 4);
            if (q == 0){
                float pm = (float)cnt * invP;
                cterm[bv] = cnt ? -pm * __logf(pm + 1e-8f) : 0.0f;
            }
        }
        __syncthreads();                       // S4

        // (f) final: mi = sum(rterm) + sum(cterm) - sum(wred); one 64-lane reduce
        if (tid < 64){
            float val = rterm[tid] + cterm[tid] - (tid < 8 ? wred[tid] : 0.0f);
            #pragma unroll
            for (int off = 32; off > 0; off >>= 1) val += __shfl_down(val, off);
            if (tid == 0) out[b * NSEL + sr6 * 6 + chalf * 3 + si] = log1pf(val);
        }
        // no barrier needed: next iter's writes to hist/distArr don't collide
        // with (f)'s reads (rterm/cterm/wred rewritten only after next S3).
    }
}

extern "C" void kernel_launch(void* const* d_in, const int* in_sizes, int n_in,
                              void* d_out, int out_size, void* d_ws, size_t ws_size,
                              hipStream_t stream) {
    const float* sino = (const float*)d_in[0];
    float* out = (float*)d_out;
    unsigned char* ws = (unsigned char*)d_ws;
    float* pmin = (float*)ws;
    float* pmax = (float*)(ws + 2048);

    k_minmax<<<NB * NPART, 256, 0, stream>>>(sino, pmin, pmax);
    k_binmi<<<NB * 12, 512, 0, stream>>>(sino, pmin, pmax, out);
}

// Round 6
// 35.913 us; speedup vs baseline: 1.2210x; 1.2210x over previous
//
#include <hip/hip_runtime.h>
#include <math.h>

#define NB   64
#define H_   384
#define W_   384
#define NR   12
#define NC   12
#define NP   144     // patches per batch
#define PE   1024    // elements per patch
#define NSEL 36
#define NPART 16     // min/max partials per batch

// ws layout:
// [0, 4096):            float pmin[64][16]
// [4096, 8192):         float pmax[64][16]
// [8192, 8192+64*144*1024): uint8 binned patches [B][144][1024]

__global__ __launch_bounds__(256) void k_minmax(const float* __restrict__ sino,
                                                float* __restrict__ pmin,
                                                float* __restrict__ pmax){
    int b = blockIdx.x >> 4;
    int part = blockIdx.x & 15;
    const float4* src = (const float4*)(sino + (size_t)b * (H_ * W_));
    int base = part * 2304 + threadIdx.x;   // 36864 float4 / batch, 2304 / part
    float mn = 1e30f, mx = -1e30f;
    #pragma unroll
    for (int k = 0; k < 9; k++){
        float4 v = src[base + k * 256];
        mn = fminf(mn, fminf(fminf(v.x, v.y), fminf(v.z, v.w)));
        mx = fmaxf(mx, fmaxf(fmaxf(v.x, v.y), fmaxf(v.z, v.w)));
    }
    #pragma unroll
    for (int off = 32; off > 0; off >>= 1){
        mn = fminf(mn, __shfl_down(mn, off));
        mx = fmaxf(mx, __shfl_down(mx, off));
    }
    __shared__ float smn[4], smx[4];
    int lane = threadIdx.x & 63, wv = threadIdx.x >> 6;
    if (lane == 0){ smn[wv] = mn; smx[wv] = mx; }
    __syncthreads();
    if (threadIdx.x == 0){
        mn = fminf(fminf(smn[0], smn[1]), fminf(smn[2], smn[3]));
        mx = fmaxf(fmaxf(smx[0], smx[1]), fmaxf(smx[2], smx[3]));
        pmin[blockIdx.x] = mn;   // race-free overwrite: no init needed
        pmax[blockIdx.x] = mx;
    }
}

__device__ inline int binval(float x, float mn, float denom){
    float nrm = (x - mn) / denom;                 // mirror reference op order exactly
    nrm = fminf(fmaxf(nrm, 0.0f), 1.0f);
    int bn = (int)(nrm * 63.0f);                  // truncation, like astype(int32)
    bn = bn < 0 ? 0 : (bn > 63 ? 63 : bn);
    return bn;
}

// 4 patches (one 32x128 strip) per block: 2304 blocks
__global__ __launch_bounds__(256) void k_bin(const float* __restrict__ sino,
                                             const float* __restrict__ pmin,
                                             const float* __restrict__ pmax,
                                             unsigned char* __restrict__ pat){
    int bid = blockIdx.x;
    int b = bid / 36;
    int rem = bid % 36;
    int prow = rem / 3;
    int strip = rem % 3;                 // 4 patches: pc = strip*4 + k
    float mn = 1e30f, mx = -1e30f;
    #pragma unroll
    for (int k = 0; k < NPART; k++){     // uniform addresses -> scalar loads
        mn = fminf(mn, pmin[b * NPART + k]);
        mx = fmaxf(mx, pmax[b * NPART + k]);
    }
    float denom = mx - mn + 1e-6f;
    int tid = threadIdx.x;
    int irow = tid >> 3;                 // 0..31 row within strip
    int tc   = tid & 7;                  // float4 index within a 32-col patch
    const float4* rowp = (const float4*)(sino + ((size_t)b * H_ + (size_t)(prow * 32 + irow)) * W_ + strip * 128);
    unsigned char* pbase = pat + ((size_t)(b * NP + prow * NC + strip * 4)) * PE + irow * 32 + tc * 4;
    #pragma unroll
    for (int k = 0; k < 4; k++){
        float4 v = rowp[tc + k * 8];
        uchar4 o;
        o.x = (unsigned char)binval(v.x, mn, denom);
        o.y = (unsigned char)binval(v.y, mn, denom);
        o.z = (unsigned char)binval(v.z, mn, denom);
        o.w = (unsigned char)binval(v.w, mn, denom);
        *(uchar4*)(pbase + (size_t)k * PE) = o;
    }
}

__device__ inline unsigned int bytesad(unsigned int a, unsigned int b, unsigned int acc){
#if __has_builtin(__builtin_amdgcn_sad_u8)
    return __builtin_amdgcn_sad_u8(a, b, acc);
#else
    unsigned int s = acc;
    #pragma unroll
    for (int k = 0; k < 4; k++){
        int av = (a >> (8 * k)) & 255;
        int bv = (b >> (8 * k)) & 255;
        int d = av - bv;
        s += (unsigned int)(d < 0 ? -d : d);
    }
    return s;
#endif
}

__global__ __launch_bounds__(256) void k_mi(const unsigned char* __restrict__ pat,
                                            float* __restrict__ out){
    int b = blockIdx.x / NSEL;
    int s = blockIdx.x % NSEL;
    int sr = (s / 6) * 2, sc = (s % 6) * 2;
    int pself = sr * NC + sc;
    const unsigned char* batch = pat + (size_t)b * NP * PE;

    __shared__ uint4 selw4[64];            // selected patch, 1024 bytes
    __shared__ unsigned int hist[4096];    // 64x64 joint histogram
    __shared__ unsigned int distArr[25];
    __shared__ int bestCid;
    __shared__ float sHx[4], sHy[4], sHxy[4];

    int tid = threadIdx.x;
    int lane = tid & 63, wv = tid >> 6;

    {   // zero hist with b128 stores
        uint4 z = {0u, 0u, 0u, 0u};
        uint4* h4 = (uint4*)hist;
        #pragma unroll
        for (int k = 0; k < 4; k++) h4[k * 256 + tid] = z;
    }
    ((unsigned int*)selw4)[tid] = ((const unsigned int*)(batch + (size_t)pself * PE))[tid];
    __syncthreads();

    // distances: 16 lanes per candidate, 4 candidates per wave, 2 rounds
    int grp = lane >> 4;                   // 0..3 candidate slot within wave
    int sl  = lane & 15;                   // 16-byte chunk index
    #pragma unroll
    for (int r = 0; r < 2; r++){
        int c = r * 16 + wv * 4 + grp;
        if (c < 25){
            int dr = c / 5 - 2, dc = c % 5 - 2;
            int rr = min(max(sr + dr, 0), NR - 1);
            int cc = min(max(sc + dc, 0), NC - 1);
            int cid = rr * NC + cc;
            const uint4* cp = (const uint4*)(batch + (size_t)cid * PE);
            unsigned int dist = 0;
            #pragma unroll
            for (int k = 0; k < 4; k++){
                uint4 cv = cp[sl + 16 * k];
                uint4 sv = selw4[sl + 16 * k];   // same addr across 16-lane groups: broadcast
                dist = bytesad(cv.x, sv.x, dist);
                dist = bytesad(cv.y, sv.y, dist);
                dist = bytesad(cv.z, sv.z, dist);
                dist = bytesad(cv.w, sv.w, dist);
            }
            #pragma unroll
            for (int off = 8; off > 0; off >>= 1) dist += __shfl_xor(dist, off);
            if (sl == 0) distArr[c] = (cid == pself) ? 0xFFFFFFFFu : dist;
        }
    }
    __syncthreads();

    if (tid == 0){
        unsigned int bd = 0xFFFFFFFFu; int bc = 0;
        #pragma unroll
        for (int c = 0; c < 25; c++){
            if (distArr[c] < bd){ bd = distArr[c]; bc = c; }   // strict <: first-min like argmin
        }
        int dr = bc / 5 - 2, dc = bc % 5 - 2;
        int rr = min(max(sr + dr, 0), NR - 1);
        int cc = min(max(sc + dc, 0), NC - 1);
        bestCid = rr * NC + cc;
    }
    __syncthreads();

    // joint histogram: each thread handles 4 elements
    {
        unsigned int bw = ((const unsigned int*)(batch + (size_t)bestCid * PE))[tid];
        unsigned int sw = ((const unsigned int*)selw4)[tid];
        #pragma unroll
        for (int k = 0; k < 4; k++){
            unsigned int sv = (sw >> (8 * k)) & 255u;
            unsigned int bv = (bw >> (8 * k)) & 255u;
            atomicAdd(&hist[sv * 64 + bv], 1u);
        }
    }
    __syncthreads();

    const float invP = 1.0f / 1024.0f;

    // fused h_xy + p_x: thread owns row r=tid>>2, quarter q=tid&3 (16 bins),
    // inner index rotated by r so a wave's 64 lanes spread over 32 banks (2-way: free).
    {
        int r = tid >> 2, q = tid & 3;
        float part = 0.0f;
        unsigned int cnt = 0;
        #pragma unroll
        for (int i = 0; i < 16; i++){
            int j = q * 16 + ((i + r) & 15);
            unsigned int c = hist[r * 64 + j];
            cnt += c;
            if (c){ float p = (float)c * invP; part -= p * __logf(p + 1e-8f); }
        }
        // h_xy block partial
        float hp = part;
        #pragma unroll
        for (int off = 32; off > 0; off >>= 1) hp += __shfl_down(hp, off);
        if (lane == 0) sHxy[wv] = hp;
        // p_x: combine 4 quarters of each row (consecutive lanes)
        cnt += __shfl_xor(cnt, 1);
        cnt += __shfl_xor(cnt, 2);
        float term = 0.0f;
        if (q == 0 && cnt){
            float pm = (float)cnt * invP;
            term = -pm * __logf(pm + 1e-8f);
        }
        #pragma unroll
        for (int off = 32; off > 0; off >>= 1) term += __shfl_down(term, off);
        if (lane == 0) sHx[wv] = term;
    }

    // p_y: 4 threads per column, stride-64 reads (4-way conflict: 1.58x, 16 reads)
    {
        int c = tid >> 2, q = tid & 3;
        unsigned int cnt = 0;
        #pragma unroll
        for (int i = 0; i < 16; i++) cnt += hist[(q * 16 + i) * 64 + c];
        cnt += __shfl_xor(cnt, 1);
        cnt += __shfl_xor(cnt, 2);
        float term = 0.0f;
        if (q == 0 && cnt){
            float pm = (float)cnt * invP;
            term = -pm * __logf(pm + 1e-8f);
        }
        #pragma unroll
        for (int off = 32; off > 0; off >>= 1) term += __shfl_down(term, off);
        if (lane == 0) sHy[wv] = term;
    }
    __syncthreads();

    if (tid == 0){
        float hx  = sHx[0] + sHx[1] + sHx[2] + sHx[3];
        float hy  = sHy[0] + sHy[1] + sHy[2] + sHy[3];
        float hxy = sHxy[0] + sHxy[1] + sHxy[2] + sHxy[3];
        float mi = hx + hy - hxy;
        out[blockIdx.x] = log1pf(mi);
    }
}

extern "C" void kernel_launch(void* const* d_in, const int* in_sizes, int n_in,
                              void* d_out, int out_size, void* d_ws, size_t ws_size,
                              hipStream_t stream) {
    const float* sino = (const float*)d_in[0];
    float* out = (float*)d_out;
    unsigned char* ws = (unsigned char*)d_ws;
    float* pmin = (float*)ws;
    float* pmax = (float*)(ws + 4096);
    unsigned char* pat = ws + 8192;

    k_minmax<<<NB * NPART, 256, 0, stream>>>(sino, pmin, pmax);
    k_bin<<<NB * 36, 256, 0, stream>>>(sino, pmin, pmax, pat);
    k_mi<<<NB * NSEL, 256, 0, stream>>>(pat, out);
}